// Round 2
// baseline (370.356 us; speedup 1.0000x reference)
//
#include <hip/hip_runtime.h>
#include <hip/hip_bf16.h>

typedef __hip_bfloat16 bf16;
typedef __attribute__((ext_vector_type(8))) short short8;
typedef __attribute__((ext_vector_type(4))) float float4v;

#define Hd 256
#define Wd 256
#define HW 65536
#define CO 64

// ---------------------------------------------------------------------------
// K1: style MLP + modulated/demodulated weights. One block per (o, s).
// wA layout: [s][kc(18)][o(64)][32], k = tap*64 + i (tap-major).
// ---------------------------------------------------------------------------
__global__ __launch_bounds__(64) void k1_style(
    const float* __restrict__ vec, const float* __restrict__ w1,
    const float* __restrict__ w2, const float* __restrict__ wconv,
    bf16* __restrict__ wA)
{
    int o = blockIdx.x;      // 0..63
    int s = blockIdx.y;      // 0..7
    int i = threadIdx.x;     // lane = input channel

    float sv[4];
#pragma unroll
    for (int q = 0; q < 4; ++q) sv[q] = vec[s * 256 + q * 64 + i];

    float hid[16];
#pragma unroll
    for (int j = 0; j < 16; ++j) {
        float p = 0.f;
#pragma unroll
        for (int q = 0; q < 4; ++q) p += sv[q] * w1[j * 256 + q * 64 + i];
#pragma unroll
        for (int off = 32; off >= 1; off >>= 1) p += __shfl_xor(p, off, 64);
        hid[j] = p > 0.f ? p : 0.1f * p;   // LeakyReLU(0.1)
    }
    float sty = 0.f;
#pragma unroll
    for (int j = 0; j < 16; ++j) sty += w2[i * 16 + j] * hid[j];
    float msty = sty + 1.0f;               // per input-channel i

    float wrow[9];
#pragma unroll
    for (int tt = 0; tt < 9; ++tt) wrow[tt] = wconv[(o * 64 + i) * 9 + tt] * msty;
    float ss = 0.f;
#pragma unroll
    for (int tt = 0; tt < 9; ++tt) ss += wrow[tt] * wrow[tt];
#pragma unroll
    for (int off = 32; off >= 1; off >>= 1) ss += __shfl_xor(ss, off, 64);
    float d = rsqrtf(ss + 1e-8f);

    bf16* wAs = wA + s * (18 * 64 * 32);
#pragma unroll
    for (int tt = 0; tt < 9; ++tt) {
        int k = tt * 64 + i;
        wAs[(k >> 5) * 2048 + o * 32 + (k & 31)] = (bf16)(wrow[tt] * d);
    }
}

// ---------------------------------------------------------------------------
// K3: FUSED ChanNorm + implicit-GEMM 3x3 conv + residual.
// Block = (s, 8 output rows, 32-px strip). Stage 10 halo rows x 34 px:
// per-thread per-pixel channel-norm (fp32 x -> bf16), ONE barrier, then
// 8 rows of barrier-free ds_read+MFMA+epilogue.
// Tile layout: [row(10)][c8(8)][wl(34)][8] bf16; ch8 stride 544B == 32 mod 128.
//
// Wave tiling 4x1: each wave owns 16 o x 32 px. A-fragments per wave =
// 18 kc x 1 = 72 VGPRs (previous 2x2 tiling needed 144 VGPRs > the 128
// cap -> compiler spilled/reloaded A inside the row loop; WRITE_SIZE
// showed ~36 MB of scratch). Same total MFMA/ds_read count; A now truly
// resident. LDS 47.6 KB -> 3 blocks/CU (launch_bounds min 3 waves/EU).
//
// Residual reconstructed from LDS: staging stashes per-pixel (mean,std);
// epilogue computes x = (nx - b[o]) / g[o] * std + mean (no HBM re-read).
// ---------------------------------------------------------------------------
#define PXB 32
#define ROWS 8
#define TR 10
#define WL 34
#define ROW_ELEMS (8 * WL * 8)   // 2176 elems = 4352 B; 10 rows = 43520 B

__global__ __launch_bounds__(256, 3) void k3_fused(
    const float* __restrict__ x, const float* __restrict__ gg,
    const float* __restrict__ bb, const bf16* __restrict__ wA,
    float* __restrict__ out)
{
    int w0 = blockIdx.x * PXB;   // 0..7 -> 0..224
    int h0 = blockIdx.y * ROWS;  // 0..31 -> 0..248
    int s  = blockIdx.z;
    int t  = threadIdx.x;
    __shared__ __align__(16) bf16 tile[TR * ROW_ELEMS];
    __shared__ float sg[64], sb[64];
    __shared__ float2 sbi[64];           // {b[o], 1/g[o]} for reconstruction
    __shared__ float2 sms[TR * WL];      // {mean, std} per staged pixel site
    if (t < 64) {
        float gv = gg[t];
        sg[t] = gv; sb[t] = bb[t];
        sbi[t] = make_float2(bb[t], 1.0f / gv);
    }
    __syncthreads();

    // ---- stage + fused ChanNorm: 340 (row,px) sites, thread-per-pixel ----
    for (int p = t; p < TR * WL; p += 256) {
        int dr = p / WL, wl = p - dr * WL;
        int grow = h0 + dr - 1, wabs = w0 + wl - 1;
        bf16* dst = &tile[dr * ROW_ELEMS + wl * 8];
        if (grow >= 0 && grow < Hd && wabs >= 0 && wabs < Wd) {
            const float* xp = x + (size_t)s * (CO * HW) + (size_t)grow * Wd + wabs;
            float v[64], s1 = 0.f, s2 = 0.f;
#pragma unroll
            for (int c = 0; c < 64; ++c) {
                float f = xp[(size_t)c * HW];
                v[c] = f; s1 += f; s2 += f * f;
            }
            float mean = s1 * (1.f / 64);
            float var  = s2 * (1.f / 64) - mean * mean;
            float rstd = rsqrtf(var + 1e-5f);
            sms[p] = make_float2(mean, sqrtf(var + 1e-5f));
#pragma unroll
            for (int c8 = 0; c8 < 8; ++c8) {
                bf16 ov[8];
#pragma unroll
                for (int k = 0; k < 8; ++k) {
                    int c = c8 * 8 + k;
                    ov[k] = (bf16)((v[c] - mean) * rstd * sg[c] + sb[c]);
                }
                *(uint4*)&dst[c8 * (WL * 8)] = *(uint4*)ov;
            }
        } else {
            sms[p] = make_float2(0.f, 0.f);
            uint4 z = make_uint4(0u, 0u, 0u, 0u);
#pragma unroll
            for (int c8 = 0; c8 < 8; ++c8) *(uint4*)&dst[c8 * (WL * 8)] = z;
        }
    }
    __syncthreads();   // the ONLY compute barrier

    int wave = t >> 6, lane = t & 63;
    int col = lane & 15, quad = lane >> 4;

    // preload A fragments: 18 kc x 1 (wave's 16-o slice), resident all rows
    const bf16* wAs = wA + s * (18 * 64 * 32);
    short8 afrag[18];
#pragma unroll
    for (int kc = 0; kc < 18; ++kc) {
        union { uint4 u; short8 s8; } a;
        a.u = *(const uint4*)&wAs[kc * 2048 + (wave * 16 + col) * 32 + quad * 8];
        afrag[kc] = a.s8;
    }

#pragma unroll 2
    for (int r = 0; r < ROWS; ++r) {
        float4v acc[2];
        acc[0] = (float4v)0.f; acc[1] = (float4v)0.f;
#pragma unroll
        for (int kc = 0; kc < 18; ++kc) {
            int tap = kc >> 1;
            int kh = tap / 3, kw = tap - kh * 3;
            int ch8 = (kc & 1) * 4 + quad;
#pragma unroll
            for (int ni = 0; ni < 2; ++ni) {
                int wl = ni * 16 + col + kw;          // <= 33
                union { uint4 u; short8 s8; } b;
                b.u = *(const uint4*)&tile[(r + kh) * ROW_ELEMS + (ch8 * WL + wl) * 8];
                acc[ni] = __builtin_amdgcn_mfma_f32_16x16x32_bf16(afrag[kc], b.s8, acc[ni], 0, 0, 0);
            }
        }
        // epilogue: residual reconstructed from LDS (no HBM re-read)
        int grow = h0 + r;
#pragma unroll
        for (int ni = 0; ni < 2; ++ni) {
            int wpx  = w0 + ni * 16 + col;
            int wl_i = ni * 16 + col + 1;
            float2 ms = sms[(r + 1) * WL + wl_i];     // {mean, std} of this pixel
#pragma unroll
            for (int rr = 0; rr < 4; ++rr) {
                int o = wave * 16 + quad * 4 + rr;
                float nxf = __bfloat162float(
                    tile[(r + 1) * ROW_ELEMS + ((o >> 3) * WL + wl_i) * 8 + (o & 7)]);
                float2 bi = sbi[o];
                float xrec = (nxf - bi.x) * bi.y * ms.y + ms.x;
                size_t idx = (size_t)(s * CO + o) * HW + (size_t)grow * Wd + wpx;
                out[idx] = acc[ni][rr] + xrec;
            }
        }
    }
}

extern "C" void kernel_launch(void* const* d_in, const int* in_sizes, int n_in,
                              void* d_out, int out_size, void* d_ws, size_t ws_size,
                              hipStream_t stream)
{
    const float* x     = (const float*)d_in[0];
    const float* vec   = (const float*)d_in[1];
    const float* g     = (const float*)d_in[2];
    const float* bb    = (const float*)d_in[3];
    const float* w1    = (const float*)d_in[4];
    const float* w2    = (const float*)d_in[5];
    const float* wconv = (const float*)d_in[6];
    float* out = (float*)d_out;

    bf16* wA = (bf16*)d_ws;    // 8*18*64*32 bf16 = 576 KB

    k1_style<<<dim3(64, 8), 64, 0, stream>>>(vec, w1, w2, wconv, wA);
    k3_fused<<<dim3(8, 32, 8), 256, 0, stream>>>(x, g, bb, wA, out);
}

// Round 3
// 362.919 us; speedup vs baseline: 1.0205x; 1.0205x over previous
//
#include <hip/hip_runtime.h>
#include <hip/hip_bf16.h>

typedef __hip_bfloat16 bf16;
typedef __attribute__((ext_vector_type(8))) short short8;
typedef __attribute__((ext_vector_type(4))) float float4v;

#define Hd 256
#define Wd 256
#define HW 65536
#define CO 64

// ---------------------------------------------------------------------------
// K1: style MLP + modulated/demodulated weights. One block per (o, s).
// wA layout: [s][kc(18)][o(64)][32], k = tap*64 + i (tap-major).
// ---------------------------------------------------------------------------
__global__ __launch_bounds__(64) void k1_style(
    const float* __restrict__ vec, const float* __restrict__ w1,
    const float* __restrict__ w2, const float* __restrict__ wconv,
    bf16* __restrict__ wA)
{
    int o = blockIdx.x;      // 0..63
    int s = blockIdx.y;      // 0..7
    int i = threadIdx.x;     // lane = input channel

    float sv[4];
#pragma unroll
    for (int q = 0; q < 4; ++q) sv[q] = vec[s * 256 + q * 64 + i];

    float hid[16];
#pragma unroll
    for (int j = 0; j < 16; ++j) {
        float p = 0.f;
#pragma unroll
        for (int q = 0; q < 4; ++q) p += sv[q] * w1[j * 256 + q * 64 + i];
#pragma unroll
        for (int off = 32; off >= 1; off >>= 1) p += __shfl_xor(p, off, 64);
        hid[j] = p > 0.f ? p : 0.1f * p;   // LeakyReLU(0.1)
    }
    float sty = 0.f;
#pragma unroll
    for (int j = 0; j < 16; ++j) sty += w2[i * 16 + j] * hid[j];
    float msty = sty + 1.0f;               // per input-channel i

    float wrow[9];
#pragma unroll
    for (int tt = 0; tt < 9; ++tt) wrow[tt] = wconv[(o * 64 + i) * 9 + tt] * msty;
    float ss = 0.f;
#pragma unroll
    for (int tt = 0; tt < 9; ++tt) ss += wrow[tt] * wrow[tt];
#pragma unroll
    for (int off = 32; off >= 1; off >>= 1) ss += __shfl_xor(ss, off, 64);
    float d = rsqrtf(ss + 1e-8f);

    bf16* wAs = wA + s * (18 * 64 * 32);
#pragma unroll
    for (int tt = 0; tt < 9; ++tt) {
        int k = tt * 64 + i;
        wAs[(k >> 5) * 2048 + o * 32 + (k & 31)] = (bf16)(wrow[tt] * d);
    }
}

// ---------------------------------------------------------------------------
// K3: FUSED ChanNorm + implicit-GEMM 3x3 conv + residual.
// Block = (s, 4 output rows, 32-px strip). Stage 6 halo rows x 34 px.
//
// Register-pressure discipline (lesson from VGPR=84 + 350 MB WRITE round:
// spilled v[64] = 134 MB each way of scratch traffic):
//  * staging: TWO-PASS over global x. Pass 1 accumulates s1/s2 only; a
//    compiler memory fence; pass 2 re-reads x (L1/L2-hot, lines touched
//    microseconds earlier), normalizes, writes bf16 LDS. No v[64] array.
//  * compute: kc-OUTER / row-INNER. A-frags loaded per-kc from L2-hot wA
//    (<=12 live at a time instead of 36 resident); acc[2][4] (32 VGPR)
//    is the only long-lived state.
//  * wave tiling back to 2x2 (mi=o-half, ni=px-half): each B ds_read
//    feeds 2 MFMAs (the 4x1 tiling doubled LDS reads + bank conflicts).
//
// Tile 6 rows -> LDS 28.8 KB -> 5 blocks/CU by LDS; launch_bounds(256,4)
// caps VGPR at 128 (guarantee only; actual occupancy from real usage).
//
// Residual reconstructed from LDS: staging stashes per-pixel (mean,std);
// epilogue computes x = (nx - b[o]) / g[o] * std + mean (no HBM re-read).
// ---------------------------------------------------------------------------
#define PXB 32
#define ROWS 4
#define TR 6
#define WL 34
#define ROW_ELEMS (8 * WL * 8)   // 2176 elems = 4352 B; 6 rows = 26112 B

__global__ __launch_bounds__(256, 4) void k3_fused(
    const float* __restrict__ x, const float* __restrict__ gg,
    const float* __restrict__ bb, const bf16* __restrict__ wA,
    float* __restrict__ out)
{
    int w0 = blockIdx.x * PXB;   // 0..7 -> 0..224
    int h0 = blockIdx.y * ROWS;  // 0..63 -> 0..252
    int s  = blockIdx.z;
    int t  = threadIdx.x;
    __shared__ __align__(16) bf16 tile[TR * ROW_ELEMS];
    __shared__ float sg[64], sb[64];
    __shared__ float2 sbi[64];           // {b[o], 1/g[o]} for reconstruction
    __shared__ float2 sms[TR * WL];      // {mean, std} per staged pixel site
    if (t < 64) {
        float gv = gg[t];
        sg[t] = gv; sb[t] = bb[t];
        sbi[t] = make_float2(bb[t], 1.0f / gv);
    }
    __syncthreads();

    // ---- stage + fused ChanNorm: 204 sites, exactly one per thread ----
    if (t < TR * WL) {
        int dr = t / WL, wl = t - dr * WL;
        int grow = h0 + dr - 1, wabs = w0 + wl - 1;
        bf16* dst = &tile[dr * ROW_ELEMS + wl * 8];
        if (grow >= 0 && grow < Hd && wabs >= 0 && wabs < Wd) {
            const float* xp = x + (size_t)s * (CO * HW) + (size_t)grow * Wd + wabs;
            // pass 1: stats only (no value array)
            float s1 = 0.f, s2 = 0.f;
#pragma unroll
            for (int c = 0; c < 64; ++c) {
                float f = xp[(size_t)c * HW];
                s1 += f; s2 += f * f;
            }
            float mean = s1 * (1.f / 64);
            float var  = s2 * (1.f / 64) - mean * mean;
            float rstd = rsqrtf(var + 1e-5f);
            sms[t] = make_float2(mean, sqrtf(var + 1e-5f));
            // forbid CSE of the x loads across passes (would rebuild v[64])
            asm volatile("" ::: "memory");
            // pass 2: re-read (L1/L2-hot), normalize, write LDS
#pragma unroll
            for (int c8 = 0; c8 < 8; ++c8) {
                bf16 ov[8];
#pragma unroll
                for (int k = 0; k < 8; ++k) {
                    int c = c8 * 8 + k;
                    float f = xp[(size_t)c * HW];
                    ov[k] = (bf16)((f - mean) * rstd * sg[c] + sb[c]);
                }
                *(uint4*)&dst[c8 * (WL * 8)] = *(uint4*)ov;
            }
        } else {
            sms[t] = make_float2(0.f, 0.f);
            uint4 z = make_uint4(0u, 0u, 0u, 0u);
#pragma unroll
            for (int c8 = 0; c8 < 8; ++c8) *(uint4*)&dst[c8 * (WL * 8)] = z;
        }
    }
    __syncthreads();   // the ONLY compute barrier

    int wave = t >> 6, lane = t & 63;
    int mi = wave & 1, ni = wave >> 1;   // wave: o in [mi*32,+32), px in [ni*16,+16)
    int col = lane & 15, quad = lane >> 4;

    const bf16* wAs = wA + s * (18 * 64 * 32);

    float4v acc[2][4];
#pragma unroll
    for (int mt = 0; mt < 2; ++mt)
#pragma unroll
        for (int r = 0; r < 4; ++r) acc[mt][r] = (float4v)0.f;

    // kc-outer: A-frags have short lives; acc[2][4] accumulates across kc.
#pragma unroll 1
    for (int kh = 0; kh < 3; ++kh) {
#pragma unroll
        for (int kw = 0; kw < 3; ++kw) {
#pragma unroll
            for (int half = 0; half < 2; ++half) {
                int kc = (kh * 3 + kw) * 2 + half;
                union { uint4 u; short8 s8; } a0, a1;
                a0.u = *(const uint4*)&wAs[kc * 2048 + (mi * 32 + col) * 32 + quad * 8];
                a1.u = *(const uint4*)&wAs[kc * 2048 + (mi * 32 + 16 + col) * 32 + quad * 8];
                int ch8 = half * 4 + quad;
#pragma unroll
                for (int r = 0; r < 4; ++r) {
                    union { uint4 u; short8 s8; } b;
                    b.u = *(const uint4*)&tile[(r + kh) * ROW_ELEMS
                                               + (ch8 * WL + ni * 16 + col + kw) * 8];
                    acc[0][r] = __builtin_amdgcn_mfma_f32_16x16x32_bf16(a0.s8, b.s8, acc[0][r], 0, 0, 0);
                    acc[1][r] = __builtin_amdgcn_mfma_f32_16x16x32_bf16(a1.s8, b.s8, acc[1][r], 0, 0, 0);
                }
            }
        }
    }

    // epilogue: residual reconstructed from LDS (no HBM re-read)
    int wpx  = w0 + ni * 16 + col;
    int wl_i = ni * 16 + col + 1;
#pragma unroll
    for (int r = 0; r < 4; ++r) {
        int grow = h0 + r;
        float2 ms = sms[(r + 1) * WL + wl_i];     // {mean, std} of this pixel
#pragma unroll
        for (int mt = 0; mt < 2; ++mt) {
#pragma unroll
            for (int rr = 0; rr < 4; ++rr) {
                int o = mi * 32 + mt * 16 + quad * 4 + rr;
                float nxf = __bfloat162float(
                    tile[(r + 1) * ROW_ELEMS + ((o >> 3) * WL + wl_i) * 8 + (o & 7)]);
                float2 bi = sbi[o];
                float xrec = (nxf - bi.x) * bi.y * ms.y + ms.x;
                size_t idx = (size_t)(s * CO + o) * HW + (size_t)grow * Wd + wpx;
                out[idx] = acc[mt][r][rr] + xrec;
            }
        }
    }
}

extern "C" void kernel_launch(void* const* d_in, const int* in_sizes, int n_in,
                              void* d_out, int out_size, void* d_ws, size_t ws_size,
                              hipStream_t stream)
{
    const float* x     = (const float*)d_in[0];
    const float* vec   = (const float*)d_in[1];
    const float* g     = (const float*)d_in[2];
    const float* bb    = (const float*)d_in[3];
    const float* w1    = (const float*)d_in[4];
    const float* w2    = (const float*)d_in[5];
    const float* wconv = (const float*)d_in[6];
    float* out = (float*)d_out;

    bf16* wA = (bf16*)d_ws;    // 8*18*64*32 bf16 = 576 KB

    k1_style<<<dim3(64, 8), 64, 0, stream>>>(vec, w1, w2, wconv, wA);
    k3_fused<<<dim3(8, 64, 8), 256, 0, stream>>>(x, g, bb, wA, out);
}

// Round 4
// 328.243 us; speedup vs baseline: 1.1283x; 1.1056x over previous
//
#include <hip/hip_runtime.h>
#include <hip/hip_bf16.h>

typedef __hip_bfloat16 bf16;
typedef __attribute__((ext_vector_type(8))) short short8;
typedef __attribute__((ext_vector_type(4))) float float4v;

#define Hd 256
#define Wd 256
#define HW 65536
#define CO 64

// ---------------------------------------------------------------------------
// K1: style MLP + modulated/demodulated weights. One block per (o, s).
// wA layout: [s][kc(18)][o(64)][32], k = tap*64 + i (tap-major).
// ---------------------------------------------------------------------------
__global__ __launch_bounds__(64) void k1_style(
    const float* __restrict__ vec, const float* __restrict__ w1,
    const float* __restrict__ w2, const float* __restrict__ wconv,
    bf16* __restrict__ wA)
{
    int o = blockIdx.x;      // 0..63
    int s = blockIdx.y;      // 0..7
    int i = threadIdx.x;     // lane = input channel

    float sv[4];
#pragma unroll
    for (int q = 0; q < 4; ++q) sv[q] = vec[s * 256 + q * 64 + i];

    float hid[16];
#pragma unroll
    for (int j = 0; j < 16; ++j) {
        float p = 0.f;
#pragma unroll
        for (int q = 0; q < 4; ++q) p += sv[q] * w1[j * 256 + q * 64 + i];
#pragma unroll
        for (int off = 32; off >= 1; off >>= 1) p += __shfl_xor(p, off, 64);
        hid[j] = p > 0.f ? p : 0.1f * p;   // LeakyReLU(0.1)
    }
    float sty = 0.f;
#pragma unroll
    for (int j = 0; j < 16; ++j) sty += w2[i * 16 + j] * hid[j];
    float msty = sty + 1.0f;               // per input-channel i

    float wrow[9];
#pragma unroll
    for (int tt = 0; tt < 9; ++tt) wrow[tt] = wconv[(o * 64 + i) * 9 + tt] * msty;
    float ss = 0.f;
#pragma unroll
    for (int tt = 0; tt < 9; ++tt) ss += wrow[tt] * wrow[tt];
#pragma unroll
    for (int off = 32; off >= 1; off >>= 1) ss += __shfl_xor(ss, off, 64);
    float d = rsqrtf(ss + 1e-8f);

    bf16* wAs = wA + s * (18 * 64 * 32);
#pragma unroll
    for (int tt = 0; tt < 9; ++tt) {
        int k = tt * 64 + i;
        wAs[(k >> 5) * 2048 + o * 32 + (k & 31)] = (bf16)(wrow[tt] * d);
    }
}

// ---------------------------------------------------------------------------
// K3: FUSED ChanNorm + implicit-GEMM 3x3 conv + residual.
// Block = (s, 8 output rows, 32-px strip). Halo tile 10 rows x 34 px.
//
// Phase-pressure discipline (R1: spilled afrag[36]; R2: spilled v[64];
// R3: two-pass thrashed L2, FETCH 2x). Resolution: the ONLY bulk store
// with the right size/BW for staging values is the LDS tile itself:
//  * staging: each thread OWNS <=2 (row,px) sites. c8-outer loop: load
//    8 channels, accumulate s1/s2 in 4 scalar regs, pack raw bf16,
//    ds_write_b128 into the tile immediately. After the loop the owner
//    normalizes its own sites IN PLACE from its register stats (no
//    barrier needed; single bf16 double-round accepted). ~20 VGPR state.
//  * compute: kc-outer / row-inner, A-frags loaded per-kc from L2-hot
//    wA (576 KB total); acc[2][8] (64 VGPR) is the only resident state.
//    2x2 wave tiling so each B ds_read feeds 2 MFMAs.
// One __syncthreads between phases. LDS 47.3 KB -> 3 blocks/CU.
//
// Residual reconstructed from LDS (mean/std stashed per site):
//   x = (nx - b[o]) / g[o] * std + mean   (no HBM re-read).
//
// Template tag = ws_size probe: <1> means ws_size >= 72 MB (enough for a
// future split-kernel packed-nx workspace). Kernel body identical.
// ---------------------------------------------------------------------------
#define PXB 32
#define ROWS 8
#define TR 10
#define WL 34
#define ROW_ELEMS (8 * WL * 8)   // 2176 elems = 4352 B; 10 rows = 43520 B

union U4 { uint4 u; bf16 h[8]; short8 s8; };

template<int WSBIG>
__global__ __launch_bounds__(256, 3) void k3_fused(
    const float* __restrict__ x, const float* __restrict__ gg,
    const float* __restrict__ bb, const bf16* __restrict__ wA,
    float* __restrict__ out)
{
    int w0 = blockIdx.x * PXB;   // 0..7 -> 0..224
    int h0 = blockIdx.y * ROWS;  // 0..31 -> 0..248
    int s  = blockIdx.z;
    int t  = threadIdx.x;
    __shared__ __align__(16) bf16 tile[TR * ROW_ELEMS];
    __shared__ float sg[64], sb[64];
    __shared__ float2 sbi[64];           // {b[o], 1/g[o]} for reconstruction
    __shared__ float2 sms[TR * WL];      // {mean, std} per staged pixel site
    if (t < 64) {
        float gv = gg[t];
        sg[t] = gv; sb[t] = bb[t];
        sbi[t] = make_float2(bb[t], 1.0f / gv);
    }
    __syncthreads();

    // ---- staging: site ownership (site0 = t, site1 = t+256) ----
    int p0 = t, p1 = t + 256;
    bool live1 = (p1 < TR * WL);         // threads 0..83 own a second site
    int dr0 = p0 / WL, wl0 = p0 - dr0 * WL;
    int dr1 = live1 ? (p1 / WL) : 0;
    int wl1 = live1 ? (p1 - dr1 * WL) : 0;
    int grow0 = h0 + dr0 - 1, wab0 = w0 + wl0 - 1;
    int grow1 = h0 + dr1 - 1, wab1 = w0 + wl1 - 1;
    bool ok0 = (grow0 >= 0 && grow0 < Hd && wab0 >= 0 && wab0 < Wd);
    bool ok1 = live1 && (grow1 >= 0 && grow1 < Hd && wab1 >= 0 && wab1 < Wd);
    const float* xp0 = x + (size_t)s * (CO * HW) + (size_t)grow0 * Wd + wab0;
    const float* xp1 = x + (size_t)s * (CO * HW) + (size_t)grow1 * Wd + wab1;
    bf16* dst0 = &tile[dr0 * ROW_ELEMS + wl0 * 8];
    bf16* dst1 = &tile[dr1 * ROW_ELEMS + wl1 * 8];

    float s1a = 0.f, s2a = 0.f, s1b = 0.f, s2b = 0.f;
#pragma unroll 1
    for (int c8 = 0; c8 < 8; ++c8) {
        U4 pa, pb;
        if (ok0) {
#pragma unroll
            for (int k = 0; k < 8; ++k) {
                float f = xp0[(size_t)(c8 * 8 + k) * HW];
                s1a += f; s2a += f * f;
                pa.h[k] = (bf16)f;
            }
        } else pa.u = make_uint4(0u, 0u, 0u, 0u);
        *(uint4*)&dst0[c8 * (WL * 8)] = pa.u;
        if (live1) {
            if (ok1) {
#pragma unroll
                for (int k = 0; k < 8; ++k) {
                    float f = xp1[(size_t)(c8 * 8 + k) * HW];
                    s1b += f; s2b += f * f;
                    pb.h[k] = (bf16)f;
                }
            } else pb.u = make_uint4(0u, 0u, 0u, 0u);
            *(uint4*)&dst1[c8 * (WL * 8)] = pb.u;
        }
    }

    // ---- owner-only in-place normalize (no barrier needed before this) ----
    {
        float mean = s1a * (1.f / 64);
        float var  = s2a * (1.f / 64) - mean * mean;
        float rstd = rsqrtf(var + 1e-5f);
        sms[p0] = ok0 ? make_float2(mean, sqrtf(var + 1e-5f)) : make_float2(0.f, 0.f);
        if (ok0) {
#pragma unroll 1
            for (int c8 = 0; c8 < 8; ++c8) {
                U4 v; v.u = *(uint4*)&dst0[c8 * (WL * 8)];
                U4 o;
#pragma unroll
                for (int k = 0; k < 8; ++k) {
                    int c = c8 * 8 + k;
                    o.h[k] = (bf16)((__bfloat162float(v.h[k]) - mean) * rstd * sg[c] + sb[c]);
                }
                *(uint4*)&dst0[c8 * (WL * 8)] = o.u;
            }
        }
    }
    if (live1) {
        float mean = s1b * (1.f / 64);
        float var  = s2b * (1.f / 64) - mean * mean;
        float rstd = rsqrtf(var + 1e-5f);
        sms[p1] = ok1 ? make_float2(mean, sqrtf(var + 1e-5f)) : make_float2(0.f, 0.f);
        if (ok1) {
#pragma unroll 1
            for (int c8 = 0; c8 < 8; ++c8) {
                U4 v; v.u = *(uint4*)&dst1[c8 * (WL * 8)];
                U4 o;
#pragma unroll
                for (int k = 0; k < 8; ++k) {
                    int c = c8 * 8 + k;
                    o.h[k] = (bf16)((__bfloat162float(v.h[k]) - mean) * rstd * sg[c] + sb[c]);
                }
                *(uint4*)&dst1[c8 * (WL * 8)] = o.u;
            }
        }
    }
    __syncthreads();   // the ONLY compute barrier

    // ---- compute: kc-outer, row-inner; acc[2][8] resident ----
    int wave = t >> 6, lane = t & 63;
    int mi = wave & 1, ni = wave >> 1;   // wave: o in [mi*32,+32), px in [ni*16,+16)
    int col = lane & 15, quad = lane >> 4;
    const bf16* wAs = wA + s * (18 * 64 * 32);

    float4v acc[2][ROWS];
#pragma unroll
    for (int mt = 0; mt < 2; ++mt)
#pragma unroll
        for (int r = 0; r < ROWS; ++r) acc[mt][r] = (float4v)0.f;

#pragma unroll 1
    for (int kh = 0; kh < 3; ++kh) {
#pragma unroll
        for (int kw = 0; kw < 3; ++kw) {
#pragma unroll
            for (int half = 0; half < 2; ++half) {
                int kc = (kh * 3 + kw) * 2 + half;
                U4 a0, a1;
                a0.u = *(const uint4*)&wAs[kc * 2048 + (mi * 32 + col) * 32 + quad * 8];
                a1.u = *(const uint4*)&wAs[kc * 2048 + (mi * 32 + 16 + col) * 32 + quad * 8];
                int ch8 = half * 4 + quad;
                const bf16* bbase = &tile[kh * ROW_ELEMS + (ch8 * WL + ni * 16 + col + kw) * 8];
#pragma unroll
                for (int r = 0; r < ROWS; ++r) {
                    U4 b; b.u = *(const uint4*)&bbase[r * ROW_ELEMS];
                    acc[0][r] = __builtin_amdgcn_mfma_f32_16x16x32_bf16(a0.s8, b.s8, acc[0][r], 0, 0, 0);
                    acc[1][r] = __builtin_amdgcn_mfma_f32_16x16x32_bf16(a1.s8, b.s8, acc[1][r], 0, 0, 0);
                }
            }
        }
    }

    // ---- epilogue: residual reconstructed from LDS (no HBM re-read) ----
    int wpx  = w0 + ni * 16 + col;
    int wl_i = ni * 16 + col + 1;
#pragma unroll
    for (int r = 0; r < ROWS; ++r) {
        int grow = h0 + r;
        float2 ms = sms[(r + 1) * WL + wl_i];     // {mean, std} of this pixel
#pragma unroll
        for (int mt = 0; mt < 2; ++mt) {
#pragma unroll
            for (int rr = 0; rr < 4; ++rr) {
                int o = mi * 32 + mt * 16 + quad * 4 + rr;
                float nxf = __bfloat162float(
                    tile[(r + 1) * ROW_ELEMS + ((o >> 3) * WL + wl_i) * 8 + (o & 7)]);
                float2 bi = sbi[o];
                float xrec = (nxf - bi.x) * bi.y * ms.y + ms.x;
                size_t idx = (size_t)(s * CO + o) * HW + (size_t)grow * Wd + wpx;
                out[idx] = acc[mt][r][rr] + xrec;
            }
        }
    }
}

extern "C" void kernel_launch(void* const* d_in, const int* in_sizes, int n_in,
                              void* d_out, int out_size, void* d_ws, size_t ws_size,
                              hipStream_t stream)
{
    const float* x     = (const float*)d_in[0];
    const float* vec   = (const float*)d_in[1];
    const float* g     = (const float*)d_in[2];
    const float* bb    = (const float*)d_in[3];
    const float* w1    = (const float*)d_in[4];
    const float* w2    = (const float*)d_in[5];
    const float* wconv = (const float*)d_in[6];
    float* out = (float*)d_out;

    bf16* wA = (bf16*)d_ws;    // 8*18*64*32 bf16 = 576 KB

    k1_style<<<dim3(64, 8), 64, 0, stream>>>(vec, w1, w2, wconv, wA);

    // ws_size probe: template tag shows up in rocprof Kernel_Name next round.
    if (ws_size >= ((size_t)72 << 20))
        k3_fused<1><<<dim3(8, 32, 8), 256, 0, stream>>>(x, g, bb, wA, out);
    else
        k3_fused<0><<<dim3(8, 32, 8), 256, 0, stream>>>(x, g, bb, wA, out);
}

// Round 5
// 314.503 us; speedup vs baseline: 1.1776x; 1.0437x over previous
//
#include <hip/hip_runtime.h>
#include <hip/hip_bf16.h>

typedef __hip_bfloat16 bf16;
typedef __attribute__((ext_vector_type(8))) short short8;
typedef __attribute__((ext_vector_type(4))) float float4v;

#define Hd 256
#define Wd 256
#define HW 65536
#define CO 64

// ---------------------------------------------------------------------------
// K1: style MLP + modulated/demodulated weights. One block per (o, s).
// wA layout: [s][kc(18)][o(64)][32], k = tap*64 + i (tap-major).
// ---------------------------------------------------------------------------
__global__ __launch_bounds__(64) void k1_style(
    const float* __restrict__ vec, const float* __restrict__ w1,
    const float* __restrict__ w2, const float* __restrict__ wconv,
    bf16* __restrict__ wA)
{
    int o = blockIdx.x;      // 0..63
    int s = blockIdx.y;      // 0..7
    int i = threadIdx.x;     // lane = input channel

    float sv[4];
#pragma unroll
    for (int q = 0; q < 4; ++q) sv[q] = vec[s * 256 + q * 64 + i];

    float hid[16];
#pragma unroll
    for (int j = 0; j < 16; ++j) {
        float p = 0.f;
#pragma unroll
        for (int q = 0; q < 4; ++q) p += sv[q] * w1[j * 256 + q * 64 + i];
#pragma unroll
        for (int off = 32; off >= 1; off >>= 1) p += __shfl_xor(p, off, 64);
        hid[j] = p > 0.f ? p : 0.1f * p;   // LeakyReLU(0.1)
    }
    float sty = 0.f;
#pragma unroll
    for (int j = 0; j < 16; ++j) sty += w2[i * 16 + j] * hid[j];
    float msty = sty + 1.0f;               // per input-channel i

    float wrow[9];
#pragma unroll
    for (int tt = 0; tt < 9; ++tt) wrow[tt] = wconv[(o * 64 + i) * 9 + tt] * msty;
    float ss = 0.f;
#pragma unroll
    for (int tt = 0; tt < 9; ++tt) ss += wrow[tt] * wrow[tt];
#pragma unroll
    for (int off = 32; off >= 1; off >>= 1) ss += __shfl_xor(ss, off, 64);
    float d = rsqrtf(ss + 1e-8f);

    bf16* wAs = wA + s * (18 * 64 * 32);
#pragma unroll
    for (int tt = 0; tt < 9; ++tt) {
        int k = tt * 64 + i;
        wAs[(k >> 5) * 2048 + o * 32 + (k & 31)] = (bf16)(wrow[tt] * d);
    }
}

// ---------------------------------------------------------------------------
// K3: FUSED ChanNorm + implicit-GEMM 3x3 conv + residual.
// Block = (s, 8 output rows, 32-px strip). Halo tile 10 rows x 34 px.
//
// Phase design (synthesis of R0-R4 evidence):
//  P1 staging  : one pass over x; per-site owner accumulates s1/s2 in 4
//                scalar regs, packs RAW bf16, ds_write_b128 immediately.
//                (R4's pattern -> ideal FETCH ~200 MB.)  No readback here.
//  (A prefetch): afrag[18][2] global loads issued right after the P1
//                barrier so L2 latency hides under P2. Resident in VGPRs
//                for the whole compute (R4's in-loop global A-loads put
//                vmcnt waits in the MFMA stream: part of the 137->161
//                regression). __launch_bounds__(256) single-arg -> cap
//                512 VGPR -> NO spill (R0-R3 all spilled something).
//  P2 rewrite  : conflict-free in-place normalize. Thread t owns channel
//                group c8s=t>>5; 32 lanes walk sites at 16 B stride
//                (2-way bank aliasing = free; R4's column readback was
//                8-way -> 10.2M conflict cycles). g/b loaded once per
//                thread. OOB sites scaled by a validity flag (keeps
//                zero-padding correct even with b[c] != 0).
//  P3 compute  : row-outer (unroll 2), kc-inner; acc[2] per row; each B
//                ds_read feeds 2 MFMAs (2x2 wave tiling).
// Two barriers total.
//
// Residual reconstructed from LDS (sms stashes mean/rstd/valid/std):
//   x = (nx - b[o]) / g[o] * std + mean   (no HBM re-read).
// ---------------------------------------------------------------------------
#define PXB 32
#define ROWS 8
#define TR 10
#define WL 34
#define NSITES (TR * WL)          // 340
#define ROW_ELEMS (8 * WL * 8)    // 2176 elems = 4352 B; 10 rows = 43520 B

union U4 { uint4 u; bf16 h[8]; short8 s8; };

__device__ __forceinline__ void k3_body(
    const float* __restrict__ x, const float* __restrict__ gg,
    const float* __restrict__ bb, const bf16* __restrict__ wA,
    float* __restrict__ out)
{
    int w0 = blockIdx.x * PXB;   // 0..7 -> 0..224
    int h0 = blockIdx.y * ROWS;  // 0..31 -> 0..248
    int s  = blockIdx.z;
    int t  = threadIdx.x;
    __shared__ __align__(16) bf16 tile[TR * ROW_ELEMS];
    __shared__ float sg[64], sb[64];
    __shared__ float2 sbi[64];           // {b[o], 1/g[o]} for reconstruction
    __shared__ float4 sms[NSITES];       // {mean, rstd, valid, std} per site
    if (t < 64) {
        float gv = gg[t];
        sg[t] = gv; sb[t] = bb[t];
        sbi[t] = make_float2(bb[t], 1.0f / gv);
    }

    // ---- P1: stage raw bf16 + register stats (site0 = t, site1 = t+256) ----
    int p0 = t, p1 = t + 256;
    bool live1 = (p1 < NSITES);          // threads 0..83 own a second site
    int dr0 = p0 / WL, wl0 = p0 - dr0 * WL;
    int dr1 = live1 ? (p1 / WL) : 0;
    int wl1 = live1 ? (p1 - dr1 * WL) : 0;
    int grow0 = h0 + dr0 - 1, wab0 = w0 + wl0 - 1;
    int grow1 = h0 + dr1 - 1, wab1 = w0 + wl1 - 1;
    bool ok0 = (grow0 >= 0 && grow0 < Hd && wab0 >= 0 && wab0 < Wd);
    bool ok1 = live1 && (grow1 >= 0 && grow1 < Hd && wab1 >= 0 && wab1 < Wd);
    const float* xp0 = x + (size_t)s * (CO * HW) + (size_t)grow0 * Wd + wab0;
    const float* xp1 = x + (size_t)s * (CO * HW) + (size_t)grow1 * Wd + wab1;
    bf16* dst0 = &tile[dr0 * ROW_ELEMS + wl0 * 8];
    bf16* dst1 = &tile[dr1 * ROW_ELEMS + wl1 * 8];

    float s1a = 0.f, s2a = 0.f, s1b = 0.f, s2b = 0.f;
#pragma unroll 1
    for (int c8 = 0; c8 < 8; ++c8) {
        U4 pa, pb;
        if (ok0) {
#pragma unroll
            for (int k = 0; k < 8; ++k) {
                float f = xp0[(size_t)(c8 * 8 + k) * HW];
                s1a += f; s2a += f * f;
                pa.h[k] = (bf16)f;
            }
        } else pa.u = make_uint4(0u, 0u, 0u, 0u);
        *(uint4*)&dst0[c8 * (WL * 8)] = pa.u;
        if (live1) {
            if (ok1) {
#pragma unroll
                for (int k = 0; k < 8; ++k) {
                    float f = xp1[(size_t)(c8 * 8 + k) * HW];
                    s1b += f; s2b += f * f;
                    pb.h[k] = (bf16)f;
                }
            } else pb.u = make_uint4(0u, 0u, 0u, 0u);
            *(uint4*)&dst1[c8 * (WL * 8)] = pb.u;
        }
    }
    {
        float mean = s1a * (1.f / 64);
        float var  = s2a * (1.f / 64) - mean * mean;
        sms[p0] = ok0 ? make_float4(mean, rsqrtf(var + 1e-5f), 1.f, sqrtf(var + 1e-5f))
                      : make_float4(0.f, 0.f, 0.f, 0.f);
    }
    if (live1) {
        float mean = s1b * (1.f / 64);
        float var  = s2b * (1.f / 64) - mean * mean;
        sms[p1] = ok1 ? make_float4(mean, rsqrtf(var + 1e-5f), 1.f, sqrtf(var + 1e-5f))
                      : make_float4(0.f, 0.f, 0.f, 0.f);
    }
    __syncthreads();   // barrier 1: all raw tiles + stats visible

    int wave = t >> 6, lane = t & 63;
    int mi = wave & 1, ni = wave >> 1;   // wave: o in [mi*32,+32), px in [ni*16,+16)
    int col = lane & 15, quad = lane >> 4;

    // ---- A prefetch (global, L2-hot): issued here so it drains under P2 ----
    const bf16* wAs = wA + s * (18 * 64 * 32);
    short8 afrag[18][2];
#pragma unroll
    for (int kc = 0; kc < 18; ++kc)
#pragma unroll
        for (int mt = 0; mt < 2; ++mt) {
            U4 a;
            a.u = *(const uint4*)&wAs[kc * 2048 + (mi * 32 + mt * 16 + col) * 32 + quad * 8];
            afrag[kc][mt] = a.s8;
        }

    // ---- P2: conflict-free in-place normalize (channel-group stripes) ----
    {
        int c8s = t >> 5, l32 = t & 31;
        float g8[8], b8[8];
#pragma unroll
        for (int k = 0; k < 8; ++k) { g8[k] = sg[c8s * 8 + k]; b8[k] = sb[c8s * 8 + k]; }
#pragma unroll 1
        for (int e = l32; e < NSITES; e += 32) {
            int dr = e / WL, wl = e - dr * WL;
            float4 ms = sms[e];
            bf16* pp = &tile[dr * ROW_ELEMS + (c8s * WL + wl) * 8];
            U4 v; v.u = *(uint4*)pp;
            U4 ov;
#pragma unroll
            for (int k = 0; k < 8; ++k) {
                float f = __bfloat162float(v.h[k]);
                ov.h[k] = (bf16)(((f - ms.x) * ms.y * g8[k] + b8[k]) * ms.z);
            }
            *(uint4*)pp = ov.u;
        }
    }
    __syncthreads();   // barrier 2: normalized tile ready

    // ---- P3: compute, row-outer, kc-inner; afrag resident ----
#pragma unroll 2
    for (int r = 0; r < ROWS; ++r) {
        float4v acc[2];
        acc[0] = (float4v)0.f; acc[1] = (float4v)0.f;
#pragma unroll
        for (int kc = 0; kc < 18; ++kc) {
            int tap = kc >> 1;
            int kh = tap / 3, kw = tap - kh * 3;
            int ch8 = (kc & 1) * 4 + quad;
            int wl = ni * 16 + col + kw;          // <= 33
            U4 b;
            b.u = *(const uint4*)&tile[(r + kh) * ROW_ELEMS + (ch8 * WL + wl) * 8];
            acc[0] = __builtin_amdgcn_mfma_f32_16x16x32_bf16(afrag[kc][0], b.s8, acc[0], 0, 0, 0);
            acc[1] = __builtin_amdgcn_mfma_f32_16x16x32_bf16(afrag[kc][1], b.s8, acc[1], 0, 0, 0);
        }
        // epilogue: residual reconstructed from LDS (no HBM re-read)
        int grow = h0 + r;
        int wpx  = w0 + ni * 16 + col;
        int wl_i = ni * 16 + col + 1;
        float4 ms = sms[(r + 1) * WL + wl_i];     // interior site: always valid
#pragma unroll
        for (int mt = 0; mt < 2; ++mt) {
#pragma unroll
            for (int rr = 0; rr < 4; ++rr) {
                int o = mi * 32 + mt * 16 + quad * 4 + rr;
                float nxf = __bfloat162float(
                    tile[(r + 1) * ROW_ELEMS + ((o >> 3) * WL + wl_i) * 8 + (o & 7)]);
                float2 bi = sbi[o];
                float xrec = (nxf - bi.x) * bi.y * ms.w + ms.x;
                size_t idx = (size_t)(s * CO + o) * HW + (size_t)grow * Wd + wpx;
                out[idx] = acc[mt][rr] + xrec;
            }
        }
    }
}

// ws_size probe: distinct NAMES (template tags were stripped in rocprof).
__global__ __launch_bounds__(256) void k3_fused_big(
    const float* __restrict__ x, const float* __restrict__ gg,
    const float* __restrict__ bb, const bf16* __restrict__ wA,
    float* __restrict__ out) { k3_body(x, gg, bb, wA, out); }

__global__ __launch_bounds__(256) void k3_fused_small(
    const float* __restrict__ x, const float* __restrict__ gg,
    const float* __restrict__ bb, const bf16* __restrict__ wA,
    float* __restrict__ out) { k3_body(x, gg, bb, wA, out); }

extern "C" void kernel_launch(void* const* d_in, const int* in_sizes, int n_in,
                              void* d_out, int out_size, void* d_ws, size_t ws_size,
                              hipStream_t stream)
{
    const float* x     = (const float*)d_in[0];
    const float* vec   = (const float*)d_in[1];
    const float* g     = (const float*)d_in[2];
    const float* bb    = (const float*)d_in[3];
    const float* w1    = (const float*)d_in[4];
    const float* w2    = (const float*)d_in[5];
    const float* wconv = (const float*)d_in[6];
    float* out = (float*)d_out;

    bf16* wA = (bf16*)d_ws;    // 8*18*64*32 bf16 = 576 KB

    k1_style<<<dim3(64, 8), 64, 0, stream>>>(vec, w1, w2, wconv, wA);

    if (ws_size >= ((size_t)80 << 20))
        k3_fused_big<<<dim3(8, 32, 8), 256, 0, stream>>>(x, g, bb, wA, out);
    else
        k3_fused_small<<<dim3(8, 32, 8), 256, 0, stream>>>(x, g, bb, wA, out);
}